// Round 4
// baseline (347.104 us; speedup 1.0000x reference)
//
#include <hip/hip_runtime.h>

#define SIG 2.8853900817779268f           // 2 * log2(e)
#define INV_SIG4 0.01442968963485602f     // 1 / SIG^4

__device__ __forceinline__ float rcp_f (float x){ return __builtin_amdgcn_rcpf(x);  }
__device__ __forceinline__ float exp2_f(float x){ return __builtin_amdgcn_exp2f(x); }

// 8 sigmoids -> one rational N/(1+D), single rcp. Caps guarantee E<=2^15 so
// the octet denominator (~E^8) stays below 2^127.
#define OCTET(K0, RES) do {                                                           \
    const float e0 = exp2_f(fmaf(spd, W8c[K0+0], fmaf(spc, W7c[K0+0], AB[K0+0])));    \
    const float e1 = exp2_f(fmaf(spd, W8c[K0+1], fmaf(spc, W7c[K0+1], AB[K0+1])));    \
    const float n01 = fmaf(Wt[K0+1], e0, fmaf(Wt[K0+0], e1, Sp8[(K0>>1)+0]));         \
    const float d01 = fmaf(e0, e1, e0 + e1);                                          \
    const float e2 = exp2_f(fmaf(spd, W8c[K0+2], fmaf(spc, W7c[K0+2], AB[K0+2])));    \
    const float e3 = exp2_f(fmaf(spd, W8c[K0+3], fmaf(spc, W7c[K0+3], AB[K0+3])));    \
    const float n23 = fmaf(Wt[K0+3], e2, fmaf(Wt[K0+2], e3, Sp8[(K0>>1)+1]));         \
    const float d23 = fmaf(e2, e3, e2 + e3);                                          \
    const float nA = fmaf(n01, d23, fmaf(n23, d01, n01 + n23));                       \
    const float dA = fmaf(d01, d23, d01 + d23);                                       \
    const float e4 = exp2_f(fmaf(spd, W8c[K0+4], fmaf(spc, W7c[K0+4], AB[K0+4])));    \
    const float e5 = exp2_f(fmaf(spd, W8c[K0+5], fmaf(spc, W7c[K0+5], AB[K0+5])));    \
    const float n45 = fmaf(Wt[K0+5], e4, fmaf(Wt[K0+4], e5, Sp8[(K0>>1)+2]));         \
    const float d45 = fmaf(e4, e5, e4 + e5);                                          \
    const float e6 = exp2_f(fmaf(spd, W8c[K0+6], fmaf(spc, W7c[K0+6], AB[K0+6])));    \
    const float e7 = exp2_f(fmaf(spd, W8c[K0+7], fmaf(spc, W7c[K0+7], AB[K0+7])));    \
    const float n67 = fmaf(Wt[K0+7], e6, fmaf(Wt[K0+6], e7, Sp8[(K0>>1)+3]));         \
    const float d67 = fmaf(e6, e7, e6 + e7);                                          \
    const float nB = fmaf(n45, d67, fmaf(n67, d45, n45 + n67));                       \
    const float dB = fmaf(d45, d67, d45 + d67);                                       \
    const float nO = fmaf(nA, dB, fmaf(nB, dA, nA + nB));                             \
    const float dO = fmaf(dA, dB, dA + dB);                                           \
    RES = fmaf(nO, rcp_f(dO + 1.0f), RES);                                            \
} while (0)

// Block: 448 threads = 7 waves; wave s handles permutation s for 64 consecutive m.
// (448,8): VGPR cap 64 -> 4 blocks/CU (LDS 37KB/block also allows 4).
__global__ __launch_bounds__(448, 8) void maron_kernel(
    const float* __restrict__ x,      // (64,14,1024)
    const float* __restrict__ W1,     // (14,16)
    const float* __restrict__ b1,     // (16)
    const float* __restrict__ W2,     // (16,1)
    const float* __restrict__ b2p,    // (1)
    const float* __restrict__ fW1,    // (120,16)
    const float* __restrict__ fb1,    // (16)
    const float* __restrict__ fW2,    // (16,1)
    const float* __restrict__ fb2p,   // (1)
    float* __restrict__ out,          // (M) out ++ (M) L
    int M)
{
    __shared__ float q_sh[64][121];   // q[m][r], stride 121 -> ds_add conflict-free
    __shared__ float h_sh[64][17];
    __shared__ float redL[7][65];

    const int tid = threadIdx.x;
    const int s   = tid >> 6;         // 0..6 (wave-uniform)
    const int ml  = tid & 63;
    const int m   = blockIdx.x * 64 + ml;

    // zero the q accumulator
    for (int i = tid; i < 64 * 121; i += 448) (&q_sh[0][0])[i] = 0.f;

    const int bb = m >> 10, tt = m & 1023;
    const float* xb = x + (size_t)bb * 14 * 1024 + tt;
    const int i0 = (7 - s) % 7;
    const int i1 = (8 - s) % 7;

    const float u = xb[(i0    ) * 1024];
    const float v = xb[(i1    ) * 1024];
    const float w = xb[(7 + i0) * 1024];
    float z = fmaxf(xb[(7 + i1) * 1024], 3.814697265625e-6f);  // 2^-18
    const float rz = rcp_f(z);

    // ---- wave-uniform constants (uniform loads -> SGPR operands) ----
    float W0c[16], W1c[16], W7c[16], W8c[16], Bs[16], cap[16], Wt[16], Sp8[8];
#pragma unroll
    for (int k = 0; k < 16; ++k) {
        W0c[k] = W1[0*16+k];
        W1c[k] = W1[1*16+k];
        W7c[k] = W1[7*16+k];
        W8c[k] = W1[8*16+k];
        float t = b1[k];
        t += W1[2*16+k] + W1[3*16+k] + W1[4*16+k] + W1[5*16+k] + W1[6*16+k];
        t += W1[9*16+k] + W1[10*16+k] + W1[11*16+k] + W1[12*16+k] + W1[13*16+k];
        Bs[k]  = SIG * t;
        cap[k] = 15.0f - SIG * (fabsf(W7c[k]) + fabsf(W8c[k]));
        Wt[k]  = -2.f * W2[k];
    }
    float C2 = b2p[0];
#pragma unroll
    for (int k = 0; k < 16; ++k) C2 += W2[k];
#pragma unroll
    for (int p = 0; p < 8; ++p) Sp8[p] = Wt[2*p] + Wt[2*p+1];

    __syncthreads();   // q_sh zeroed before any ds_add

    float Lsum = 0.f;
    const float z2 = z * z, z4 = z2 * z2;
    float zna = SIG * (z4 * z2 * z);   // SIG * z^(7-a), a=0
    float spa = SIG;                   // SIG * u^a
    float* qrow = &q_sh[ml][0];

    int r = 0;
    for (int a = 0; a <= 7; ++a) {
        float spb = SIG;               // SIG * v^b
        float znb = zna;               // SIG * z^(7-a-b)
        const float paS = spa * INV_SIG4;

        for (int bi = 0; bi <= 7 - a; ++bi) {
            float AB[16];
#pragma unroll
            for (int k = 0; k < 16; ++k)
                AB[k] = fminf(fmaf(spb, W1c[k], fmaf(spa, W0c[k], Bs[k])), cap[k]);

            const float pab2 = paS * spb;     // u^a v^b / SIG^2
            float spc = SIG;                  // SIG * w^c
            float spd = znb;                  // SIG * z^d
            const int cmax = 7 - a - bi;

            for (int ci = 0; ci <= cmax; ++ci, ++r) {
                float mulnn = C2;
                OCTET(0, mulnn);
                OCTET(8, mulnn);
                const float mulT = pab2 * (spc * spd);   // u^a v^b w^c z^d
                Lsum += fabsf(mulT - mulnn);
                atomicAdd(qrow + r, mulnn);              // ds_add_f32, conflict-free
                spc *= w;
                spd *= rz;
            }
            spb *= v;
            znb *= rz;
        }
        spa *= u;
        zna *= rz;
    }
    redL[s][ml] = Lsum;
    __syncthreads();

    // q @ feat_W1 : 1024 (m,k) dots of length 120; k wave-uniform per sweep
    for (int task = tid; task < 1024; task += 448) {
        const int mm = task & 63;
        const int k  = task >> 6;
        const float* col = fW1 + k;
        float d0 = 0.f, d1 = 0.f, d2 = 0.f, d3 = 0.f;
#pragma unroll
        for (int rr = 0; rr < 120; rr += 4) {
            d0 = fmaf(q_sh[mm][rr+0], col[(rr+0) << 4], d0);
            d1 = fmaf(q_sh[mm][rr+1], col[(rr+1) << 4], d1);
            d2 = fmaf(q_sh[mm][rr+2], col[(rr+2) << 4], d2);
            d3 = fmaf(q_sh[mm][rr+3], col[(rr+3) << 4], d3);
        }
        h_sh[mm][k] = (d0 + d1) + (d2 + d3);
    }
    __syncthreads();

    if (tid < 64) {
        float Lt = redL[0][tid];
#pragma unroll
        for (int ss = 1; ss < 7; ++ss) Lt += redL[ss][tid];

        float o = fb2p[0];
        float s3 = 0.f;
#pragma unroll
        for (int k = 0; k < 16; ++k) {
            const float a2 = SIG * (h_sh[tid][k] + fb1[k]);
            const float rk = rcp_f(exp2_f(a2) + 1.f);
            s3 = fmaf(fW2[k], rk, s3);
            o += fW2[k];
        }
        o = fmaf(-2.f, s3, o);

        const int mo = blockIdx.x * 64 + tid;
        out[mo]     = o;
        out[M + mo] = Lt * (1.f / 120.f);
    }
}

extern "C" void kernel_launch(void* const* d_in, const int* in_sizes, int n_in,
                              void* d_out, int out_size, void* d_ws, size_t ws_size,
                              hipStream_t stream) {
    const float* x   = (const float*)d_in[0];
    const float* W1  = (const float*)d_in[1];
    const float* b1  = (const float*)d_in[2];
    const float* W2  = (const float*)d_in[3];
    const float* b2  = (const float*)d_in[4];
    const float* fW1 = (const float*)d_in[5];
    const float* fb1 = (const float*)d_in[6];
    const float* fW2 = (const float*)d_in[7];
    const float* fb2 = (const float*)d_in[8];

    const int M = out_size / 2;           // 65536
    const int blocks = M / 64;            // 1024

    maron_kernel<<<blocks, 448, 0, stream>>>(x, W1, b1, W2, b2, fW1, fb1, fW2, fb2,
                                             (float*)d_out, M);
}

// Round 5
// 252.734 us; speedup vs baseline: 1.3734x; 1.3734x over previous
//
#include <hip/hip_runtime.h>

#define SIG 2.8853900817779268f           // 2 * log2(e)
#define INV_SIG4 0.01442968963485602f     // 1 / SIG^4

__device__ __forceinline__ float rcp_f (float x){ return __builtin_amdgcn_rcpf(x);  }
__device__ __forceinline__ float exp2_f(float x){ return __builtin_amdgcn_exp2f(x); }

// Block: 448 threads = 7 waves; wave s handles permutation s for 64 consecutive m.
// (448,7): VGPR cap 73 -> full 7 waves/SIMD residency (1024 blocks = 4/CU).
__global__ __launch_bounds__(448, 7) void maron_kernel(
    const float* __restrict__ x,      // (64,14,1024)
    const float* __restrict__ W1,     // (14,16)
    const float* __restrict__ b1,     // (16)
    const float* __restrict__ W2,     // (16,1)
    const float* __restrict__ b2p,    // (1)
    const float* __restrict__ fW1,    // (120,16)
    const float* __restrict__ fb1,    // (16)
    const float* __restrict__ fW2,    // (16,1)
    const float* __restrict__ fb2p,   // (1)
    float* __restrict__ out,          // (M) out ++ (M) L
    int M)
{
    __shared__ float red[7][64][17];  // stride 17 (odd) -> conflict-free

    const int tid = threadIdx.x;
    const int s   = tid >> 6;         // 0..6 (wave-uniform)
    const int ml  = tid & 63;
    const int m   = blockIdx.x * 64 + ml;
    const int bb  = m >> 10, tt = m & 1023;

    const float* xb = x + (size_t)bb * 14 * 1024 + tt;
    const int i0 = (7 - s) % 7;
    const int i1 = (8 - s) % 7;

    const float u = xb[(i0    ) * 1024];
    const float v = xb[(i1    ) * 1024];
    const float w = xb[(7 + i0) * 1024];
    float z = fmaxf(xb[(7 + i1) * 1024], 3.814697265625e-6f);  // 2^-18
    const float rz = rcp_f(z);

    // C2 = b2 + sum W2 (wave-uniform; W2/b2 stay in SGPRs via s_load)
    float C2 = b2p[0];
#pragma unroll
    for (int k = 0; k < 16; ++k) C2 += W2[k];

    // AB[k] = SIG*(b1 + sum_{j!=7,8} W1[j,k] * p_j) evolved incrementally.
    // Init at a=b=0: all active powers are 1.
    float AB[16];
#pragma unroll
    for (int k = 0; k < 16; ++k) {
        float t = b1[k] + W1[0*16+k] + W1[1*16+k];
        t += W1[2*16+k] + W1[3*16+k] + W1[4*16+k] + W1[5*16+k] + W1[6*16+k];
        t += W1[9*16+k] + W1[10*16+k] + W1[11*16+k] + W1[12*16+k] + W1[13*16+k];
        AB[k] = SIG * t;
    }

    float acc[16];
#pragma unroll
    for (int k = 0; k < 16; ++k) acc[k] = 0.f;
    float Lsum = 0.f;

    const float z2 = z * z, z4 = z2 * z2;
    float zna = SIG * (z4 * z2 * z);   // SIG * z^(7-a)
    float spa = SIG;                   // SIG * u^a
    float spb = SIG;                   // SIG * v^b
    float znb = zna;                   // SIG * z^(7-a-b)

    int r = 0;
    for (int a = 0; a <= 7; ++a) {
        for (int bi = 0; bi <= 7 - a; ++bi) {
            const float pab2 = (spa * spb) * INV_SIG4;  // u^a v^b / SIG^2
            float spc = SIG;                            // SIG * w^c
            float spd = znb;                            // SIG * z^d
            const int cmax = 7 - a - bi;

            for (int ci = 0; ci <= cmax; ++ci, ++r) {
                const float* frow = fW1 + (r << 4);     // wave-uniform -> s_load

                // mulnn = C2 - 2 * sum_k W2[k] / (1 + 2^tk); quads of 4 share one rcp
                float s2 = 0.f;
#pragma unroll
                for (int qd = 0; qd < 4; ++qd) {
                    const int k0 = qd * 4;
                    const float t0 = fmaf(spd, W1[8*16+k0+0], fmaf(spc, W1[7*16+k0+0], AB[k0+0]));
                    const float t1 = fmaf(spd, W1[8*16+k0+1], fmaf(spc, W1[7*16+k0+1], AB[k0+1]));
                    const float t2 = fmaf(spd, W1[8*16+k0+2], fmaf(spc, W1[7*16+k0+2], AB[k0+2]));
                    const float t3 = fmaf(spd, W1[8*16+k0+3], fmaf(spc, W1[7*16+k0+3], AB[k0+3]));
                    const float e0p = exp2_f(t0) + 1.f;   // 1 + E0
                    const float e1p = exp2_f(t1) + 1.f;
                    const float e2p = exp2_f(t2) + 1.f;
                    const float e3p = exp2_f(t3) + 1.f;
                    const float n01 = fmaf(W2[k0+1], e0p, W2[k0+0] * e1p);
                    const float d01 = e0p * e1p;
                    const float n23 = fmaf(W2[k0+3], e2p, W2[k0+2] * e3p);
                    const float d23 = e2p * e3p;
                    const float Nq = fmaf(n01, d23, n23 * d01);
                    const float Dq = d01 * d23;
                    s2 = fmaf(Nq, rcp_f(Dq), s2);
                }
                const float mulnn = fmaf(-2.f, s2, C2);
                const float mulT  = pab2 * (spc * spd);   // u^a v^b w^c z^d
                Lsum += fabsf(mulT - mulnn);

#pragma unroll
                for (int k = 0; k < 16; ++k) acc[k] = fmaf(mulnn, frow[k], acc[k]);

                spc *= w;
                spd *= rz;
            }
            // b -> b+1 : AB tracks spb * W1row1
            const float dspb = spb * (v - 1.f);
#pragma unroll
            for (int k = 0; k < 16; ++k) AB[k] = fmaf(dspb, W1[1*16+k], AB[k]);
            spb *= v;
            znb *= rz;
        }
        // a -> a+1 : bump spa contribution, reset spb contribution to SIG
        const float dspa = spa * (u - 1.f);
        const float dB   = SIG - spb;
#pragma unroll
        for (int k = 0; k < 16; ++k)
            AB[k] = fmaf(dspa, W1[0*16+k], fmaf(dB, W1[1*16+k], AB[k]));
        spa *= u;
        zna *= rz;
        spb = SIG;
        znb = zna;
    }

    // reduce the 7 permutations
#pragma unroll
    for (int k = 0; k < 16; ++k) red[s][ml][k] = acc[k];
    red[s][ml][16] = Lsum;
    __syncthreads();

    if (tid < 64) {
        float aq[16];
#pragma unroll
        for (int k = 0; k < 16; ++k) aq[k] = red[0][tid][k];
        float Lt = red[0][tid][16];
#pragma unroll
        for (int ss = 1; ss < 7; ++ss) {
#pragma unroll
            for (int k = 0; k < 16; ++k) aq[k] += red[ss][tid][k];
            Lt += red[ss][tid][16];
        }

        float o = fb2p[0];
        float s3 = 0.f;
#pragma unroll
        for (int k = 0; k < 16; ++k) {
            const float a2 = SIG * (aq[k] + fb1[k]);
            const float rk = rcp_f(exp2_f(a2) + 1.f);
            s3 = fmaf(fW2[k], rk, s3);
            o += fW2[k];
        }
        o = fmaf(-2.f, s3, o);

        const int mo = blockIdx.x * 64 + tid;
        out[mo]     = o;
        out[M + mo] = Lt * (1.f / 120.f);
    }
}

extern "C" void kernel_launch(void* const* d_in, const int* in_sizes, int n_in,
                              void* d_out, int out_size, void* d_ws, size_t ws_size,
                              hipStream_t stream) {
    const float* x   = (const float*)d_in[0];
    const float* W1  = (const float*)d_in[1];
    const float* b1  = (const float*)d_in[2];
    const float* W2  = (const float*)d_in[3];
    const float* b2  = (const float*)d_in[4];
    const float* fW1 = (const float*)d_in[5];
    const float* fb1 = (const float*)d_in[6];
    const float* fW2 = (const float*)d_in[7];
    const float* fb2 = (const float*)d_in[8];

    const int M = out_size / 2;           // 65536
    const int blocks = M / 64;            // 1024

    maron_kernel<<<blocks, 448, 0, stream>>>(x, W1, b1, W2, b2, fW1, fb1, fW2, fb2,
                                             (float*)d_out, M);
}